// Round 17
// baseline (68.059 us; speedup 1.0000x reference)
//
#include <hip/hip_runtime.h>

#define BATCH 1024
#define INSZ 4096
#define NH 8
#define TPB 256
#define LDT 40   // xn [128][32] padded stride (overlay)

typedef __attribute__((ext_vector_type(8))) __bf16 bf16x8;
typedef __attribute__((ext_vector_type(4))) __bf16 bf16x4;
typedef __attribute__((ext_vector_type(4))) float f32x4;

// ws layout (bf16 elems):
//   M  [0,8192)      per-head M_h[e'][e] = CQ * sum_f Wk[f][e]*Wq[f][e']  (8x 32x32)
//   C  [8192,8704)   c padded [16][32]: rows h<8 = CQ*Wq_h^T*bk_h, rows 8-15 = 0
//   wv [16384,24576) bf16 copy of wv
//   wo [24576,32768) bf16 copy of wo
// LDS layout (bf16 elems):
//   PP0 [0,18432)     prod partials parity0: [4 w][128 i][36] (stride 36 = 72B
//                     rows: bank-spread, 8B-aligned b64); xn [0,5120) overlays
//   PP1 [18432,36864) prod partials parity1
//   SD  [36864,38912) s[8 h][128 i] f32 (query-bias term, computed once)
//   RD  [38912,38944) LN reduction scratch
// Total 38944 elems = 77888 B -> 2 blocks/CU.
#define PP0 0
#define PP1 18432
#define SD 36864
#define RD 38912
#define PPW 4608   // per-wave stride = 128*36

// 1/sqrt(32) * log2(e). Softmax over QUERY axis i: all score terms constant
// in i cancel exactly, so scores reduce to xn_i M_h xn_j^T + c_h.xn_i.
#define CQ 0.25505644061151687f

// ONE prep kernel (72 blocks): blocks 0-63 convert wv/wo to bf16; blocks
// 64-71 compute M_h = CQ*Wk_h^T*Wq_h and c_h = CQ*Wq_h^T*bk_h.
__global__ void prep(const float* __restrict__ wq, const float* __restrict__ wk,
                     const float* __restrict__ bk, const float* __restrict__ wv,
                     const float* __restrict__ wo, __bf16* __restrict__ ws) {
  const int t = threadIdx.x;
  if (blockIdx.x < 64) {
    int i = blockIdx.x * TPB + t;  // 0..16383
    ws[16384 + i] = (__bf16)((i < 8192) ? wv[i] : wo[i - 8192]);
    return;
  }
  __shared__ float Q[1024], K[1024];
  const int h = blockIdx.x - 64;
  for (int z = t; z < 1024; z += TPB) { Q[z] = wq[h * 1024 + z]; K[z] = wk[h * 1024 + z]; }
  __syncthreads();
#pragma unroll
  for (int z = 0; z < 4; ++z) {
    int idx = t * 4 + z;            // 0..1023
    int ep = idx >> 5, e = idx & 31;
    float acc = 0.f;
#pragma unroll
    for (int f = 0; f < 32; ++f) acc += K[f * 32 + e] * Q[f * 32 + ep];
    ws[h * 1024 + ep * 32 + e] = (__bf16)(acc * CQ);  // M[e'][e]
  }
  if (t < 32) {
    float acc = 0.f;
#pragma unroll
    for (int f = 0; f < 32; ++f) acc += Q[f * 32 + t] * bk[h * 32 + f];
    ws[8192 + h * 32 + t] = (__bf16)(acc * CQ);       // C row h
  }
  if (h == 0) ws[8448 + t] = (__bf16)0.f;             // C rows 8..15 zero
}

// 16-lane butterfly sum on the VALU pipe (DPP), no LDS traffic.
__device__ __forceinline__ float row_reduce_add16(float v) {
  int t;
  t = __builtin_amdgcn_update_dpp(0, __float_as_int(v), 0xB1, 0xF, 0xF, true);
  v += __int_as_float(t);
  t = __builtin_amdgcn_update_dpp(0, __float_as_int(v), 0x4E, 0xF, 0xF, true);
  v += __int_as_float(t);
  t = __builtin_amdgcn_update_dpp(0, __float_as_int(v), 0x141, 0xF, 0xF, true);
  v += __int_as_float(t);
  t = __builtin_amdgcn_update_dpp(0, __float_as_int(v), 0x140, 0xF, 0xF, true);
  v += __int_as_float(t);
  return v;
}

__global__ __launch_bounds__(TPB, 2) void mha_fused(
    const float* __restrict__ x, const float* __restrict__ gamma,
    const float* __restrict__ beta, const float* __restrict__ bv,
    const float* __restrict__ bo, const __bf16* __restrict__ wbf,
    float* __restrict__ out) {
  __shared__ __align__(16) __bf16 R[38944];  // 77888 B

  const int b = blockIdx.x;
  const int tid = threadIdx.x;
  const int lane = tid & 63;
  const int wid = tid >> 6;   // 4 waves; wave w owns key-rows j in [32w, 32w+32)
  const int l15 = lane & 15;
  const int lh = lane >> 4;   // 0..3

  const __bf16* wvb = wbf + 16384;
  const __bf16* wob = wbf + 24576;  // [32][256] row-major

  const float* xb = x + b * INSZ;
  const f32x4 fz = {0.f, 0.f, 0.f, 0.f};

  float* red2 = (float*)&R[RD];
  float* sp = (float*)&R[SD];  // s[h][i]

  // ---------------- LayerNorm ----------------
  float xv[16];
  float s = 0.f, sq = 0.f;
#pragma unroll
  for (int i = 0; i < 4; ++i) {
    float4 a = ((const float4*)(xb + tid * 16))[i];
    xv[4 * i] = a.x; xv[4 * i + 1] = a.y; xv[4 * i + 2] = a.z; xv[4 * i + 3] = a.w;
  }
#pragma unroll
  for (int i = 0; i < 16; ++i) { s += xv[i]; sq += xv[i] * xv[i]; }
#pragma unroll
  for (int o = 32; o > 0; o >>= 1) { s += __shfl_down(s, o); sq += __shfl_down(sq, o); }
  if (lane == 0) { red2[wid] = s; red2[4 + wid] = sq; }
  __syncthreads();
  s = red2[0] + red2[1] + red2[2] + red2[3];
  sq = red2[4] + red2[5] + red2[6] + red2[7];
  const float mu = s * (1.f / INSZ);
  const float var = fmaxf(sq * (1.f / INSZ) - mu * mu, 0.f);
  const float rs = rsqrtf(var + 1e-5f);
  {
    int base = tid * 16;
#pragma unroll
    for (int i = 0; i < 4; ++i) {
      float4 g4 = ((const float4*)(gamma + base))[i];
      float4 b4 = ((const float4*)(beta + base))[i];
      float gg[4] = {g4.x, g4.y, g4.z, g4.w};
      float bb[4] = {b4.x, b4.y, b4.z, b4.w};
#pragma unroll
      for (int k = 0; k < 4; ++k) {
        int idx = base + 4 * i + k;
        float xn = (xv[4 * i + k] - mu) * rs * gg[k] + bb[k];
        R[PP0 + (idx >> 5) * LDT + (idx & 31)] = (__bf16)xn;  // overlay, dies pre-loop
      }
    }
  }
  __syncthreads();  // P1: xn visible to all waves

  const int r0 = wid * 32;

  // xn B-frags for scores, PERMUTED cols (u -> e'(u)=(u>=4)*16+lh*4+(u&3)),
  // all 128 query rows — head-invariant, registers forever.
  bf16x8 xq[8];
#pragma unroll
  for (int it = 0; it < 8; ++it) {
    bf16x4 lo = *(const bf16x4*)&R[PP0 + (it * 16 + l15) * LDT + lh * 4];
    bf16x4 hi = *(const bf16x4*)&R[PP0 + (it * 16 + l15) * LDT + 16 + lh * 4];
#pragma unroll
    for (int u = 0; u < 4; ++u) { xq[it][u] = lo[u]; xq[it][4 + u] = hi[u]; }
  }
  // xn natural frags of own rows.
  bf16x8 tA0 = *(const bf16x8*)&R[PP0 + (r0 + l15) * LDT + lh * 8];
  bf16x8 tA1 = *(const bf16x8*)&R[PP0 + (r0 + 16 + l15) * LDT + lh * 8];

  // s[h][i] = c_h . xn_i — one MFMA pair: D[i][h] = mfma(xn_own, Cpad)
  {
    bf16x8 cf = *(const bf16x8*)&wbf[8192 + l15 * 32 + lh * 8];
    f32x4 s0 = __builtin_amdgcn_mfma_f32_16x16x32_bf16(tA0, cf, fz, 0, 0, 0);
    f32x4 s1 = __builtin_amdgcn_mfma_f32_16x16x32_bf16(tA1, cf, fz, 0, 0, 0);
    if (l15 < 8) {
#pragma unroll
      for (int r = 0; r < 4; ++r) {
        sp[l15 * 128 + r0 + lh * 4 + r] = s0[r];
        sp[l15 * 128 + r0 + 16 + lh * 4 + r] = s1[r];
      }
    }
  }

  // oacc[qt][nt]: D[q][e'], q=r0+qt*16+lh*4+r, e'=nt*16+l15; seeded with bo.
  f32x4 oacc[2][2];
  {
    float b0 = bo[l15], b1 = bo[16 + l15];
#pragma unroll
    for (int qt = 0; qt < 2; ++qt) {
      oacc[qt][0] = f32x4{b0, b0, b0, b0};
      oacc[qt][1] = f32x4{b1, b1, b1, b1};
    }
  }

  // Per-head register fragments (current + next, explicit swap).
  bf16x8 tka0, tka1, vpa0, vpa1;
  bf16x8 tka0n, tka1n, vpa0n, vpa1n;

  // t-proj (scores A-frags) + v-proj (PV A-frags) — ALL register outputs.
  auto do_proj = [&](int hh) {
    const __bf16* Mh = wbf + hh * 1024;
    bf16x8 m0 = *(const bf16x8*)&Mh[(l15) * 32 + lh * 8];
    bf16x8 m1 = *(const bf16x8*)&Mh[(16 + l15) * 32 + lh * 8];
    // t^T[e'][j]: D cols j = own rows, e' reg-held.
    f32x4 d00 = __builtin_amdgcn_mfma_f32_16x16x32_bf16(m0, tA0, fz, 0, 0, 0);
    f32x4 d01 = __builtin_amdgcn_mfma_f32_16x16x32_bf16(m0, tA1, fz, 0, 0, 0);
    f32x4 d10 = __builtin_amdgcn_mfma_f32_16x16x32_bf16(m1, tA0, fz, 0, 0, 0);
    f32x4 d11 = __builtin_amdgcn_mfma_f32_16x16x32_bf16(m1, tA1, fz, 0, 0, 0);
#pragma unroll
    for (int u = 0; u < 4; ++u) {
      tka0n[u] = (__bf16)d00[u]; tka0n[4 + u] = (__bf16)d10[u];
      tka1n[u] = (__bf16)d01[u]; tka1n[4 + u] = (__bf16)d11[u];
    }
    // v-proj: D[s][f], s = own key rows, f = e; pack A-frags for PV:
    // vpa_et[u] = v[j_local(u) = (u>=4)*16+lh*4+(u&3)][e = et*16+l15]
#pragma unroll
    for (int et = 0; et < 2; ++et) {
      int f0 = hh * 32 + et * 16;
      bf16x8 wvf = *(const bf16x8*)&wvb[(f0 + l15) * 32 + lh * 8];
      float bvs = bv[f0 + l15];
      f32x4 bv4 = {bvs, bvs, bvs, bvs};
      f32x4 dv0 = __builtin_amdgcn_mfma_f32_16x16x32_bf16(tA0, wvf, bv4, 0, 0, 0);
      f32x4 dv1 = __builtin_amdgcn_mfma_f32_16x16x32_bf16(tA1, wvf, bv4, 0, 0, 0);
      bf16x8 vp;
#pragma unroll
      for (int u = 0; u < 4; ++u) { vp[u] = (__bf16)dv0[u]; vp[4 + u] = (__bf16)dv1[u]; }
      if (et == 0) vpa0n = vp; else vpa1n = vp;
    }
  };

  do_proj(0);
  tka0 = tka0n; tka1 = tka1n; vpa0 = vpa0n; vpa1 = vpa1n;
  __syncthreads();  // P2: sp visible; also orders xn reads before PP0 writes

  for (int h = 0; h < NH; ++h) {
    __bf16* PPp = &R[(h & 1) ? PP1 : PP0];

    // ---------- [1] scoresT = t·xn^T : 100% register operands ----------
    // st_[mt][it]: D[j][i], j = r0+mt*16+lh*4+r, i = it*16+l15
    f32x4 st_[2][8];
    __builtin_amdgcn_s_setprio(1);
#pragma unroll
    for (int it = 0; it < 8; ++it) {
      st_[0][it] = __builtin_amdgcn_mfma_f32_16x16x32_bf16(tka0, xq[it], fz, 0, 0, 0);
      st_[1][it] = __builtin_amdgcn_mfma_f32_16x16x32_bf16(tka1, xq[it], fz, 0, 0, 0);
    }
    __builtin_amdgcn_s_setprio(0);

    // ---------- [2] project NEXT head (fills scores MFMA latency) ----------
    if (h < NH - 1) do_proj(h + 1);

    // ---------- [3] softmax over query axis: + s_i bias, exp2, DPP sums ----------
    // Denominators are per column j = wave-local (own 32 keys, all 128 i).
    float sv[8];
#pragma unroll
    for (int it = 0; it < 8; ++it) sv[it] = sp[h * 128 + it * 16 + l15];
    float inv[2][4];
#pragma unroll
    for (int mt = 0; mt < 2; ++mt)
#pragma unroll
      for (int r = 0; r < 4; ++r) {
        float ssum = 0.f;
#pragma unroll
        for (int it = 0; it < 8; ++it) {
          float e = __builtin_amdgcn_exp2f(st_[mt][it][r] + sv[it]);
          st_[mt][it][r] = e;
          ssum += e;
        }
        ssum = row_reduce_add16(ssum);
        inv[mt][r] = __builtin_amdgcn_rcpf(ssum);
      }

    // ---------- [4] partial PV over own keys: pure register MFMAs ----------
    // B-frag eb[u] = P[j_local(u)][i]; A-frag vpa_et (same virtual-k map).
    // p2[et][it]: D[e][i], e = et*16+lh*4+r, i = it*16+l15.
    f32x4 p2[2][8];
    __builtin_amdgcn_s_setprio(1);
#pragma unroll
    for (int it = 0; it < 8; ++it) {
      bf16x8 eb;
#pragma unroll
      for (int u = 0; u < 4; ++u) {
        eb[u] = (__bf16)(st_[0][it][u] * inv[0][u]);
        eb[4 + u] = (__bf16)(st_[1][it][u] * inv[1][u]);
      }
      p2[0][it] = __builtin_amdgcn_mfma_f32_16x16x32_bf16(vpa0, eb, fz, 0, 0, 0);
      p2[1][it] = __builtin_amdgcn_mfma_f32_16x16x32_bf16(vpa1, eb, fz, 0, 0, 0);
    }
    __builtin_amdgcn_s_setprio(0);

    // ---------- [5] partial store: [i][c], c = lh*8+et*4+r encodes e ----------
#pragma unroll
    for (int it = 0; it < 8; ++it) {
      bf16x4 lo, hi;
#pragma unroll
      for (int r = 0; r < 4; ++r) {
        lo[r] = (__bf16)p2[0][it][r];
        hi[r] = (__bf16)p2[1][it][r];
      }
      int base = wid * PPW + (it * 16 + l15) * 36 + lh * 8;
      *(bf16x4*)&PPp[base] = lo;
      *(bf16x4*)&PPp[base + 4] = hi;
    }
    __syncthreads();  // the ONLY barrier per head: partials ready

    // ---------- [6] read+sum partials -> pa (cols lh*8..+7 = e(u) order) ----------
    // ---------- [7] outproj from registers ----------
    bf16x4 w0lo = *(const bf16x4*)&wob[(l15) * 256 + h * 32 + lh * 4];
    bf16x4 w0hi = *(const bf16x4*)&wob[(l15) * 256 + h * 32 + 16 + lh * 4];
    bf16x4 w1lo = *(const bf16x4*)&wob[(16 + l15) * 256 + h * 32 + lh * 4];
    bf16x4 w1hi = *(const bf16x4*)&wob[(16 + l15) * 256 + h * 32 + 16 + lh * 4];
    bf16x8 wof0, wof1;
#pragma unroll
    for (int u = 0; u < 4; ++u) {
      wof0[u] = w0lo[u]; wof0[4 + u] = w0hi[u];
      wof1[u] = w1lo[u]; wof1[4 + u] = w1hi[u];
    }
#pragma unroll
    for (int qt = 0; qt < 2; ++qt) {
      float acc8[8];
#pragma unroll
      for (int u = 0; u < 8; ++u) acc8[u] = 0.f;
#pragma unroll
      for (int w = 0; w < 4; ++w) {
        int base = w * PPW + (r0 + qt * 16 + l15) * 36 + lh * 8;
        bf16x4 a = *(const bf16x4*)&PPp[base];
        bf16x4 c = *(const bf16x4*)&PPp[base + 4];
#pragma unroll
        for (int u = 0; u < 4; ++u) {
          acc8[u] += (float)a[u];
          acc8[4 + u] += (float)c[u];
        }
      }
      bf16x8 pa;
#pragma unroll
      for (int u = 0; u < 8; ++u) pa[u] = (__bf16)acc8[u];
      oacc[qt][0] = __builtin_amdgcn_mfma_f32_16x16x32_bf16(pa, wof0, oacc[qt][0], 0, 0, 0);
      oacc[qt][1] = __builtin_amdgcn_mfma_f32_16x16x32_bf16(pa, wof1, oacc[qt][1], 0, 0, 0);
    }

    // rotate next-head fragments into place
    tka0 = tka0n; tka1 = tka1n; vpa0 = vpa0n; vpa1 = vpa1n;
    // No second barrier: PP[p] is re-written only at h+2, after barrier(h+1)
    // orders all waves past this head's reads.
  }

  // ---------------- epilogue: + x (bo already seeded) ----------------
#pragma unroll
  for (int qt = 0; qt < 2; ++qt)
#pragma unroll
    for (int nt = 0; nt < 2; ++nt)
#pragma unroll
      for (int r = 0; r < 4; ++r) {
        int s_ = r0 + qt * 16 + lh * 4 + r;
        int e_ = nt * 16 + l15;
        int idx = s_ * 32 + e_;
        out[b * INSZ + idx] = oacc[qt][nt][r] + xb[idx];
      }
}

extern "C" void kernel_launch(void* const* d_in, const int* in_sizes, int n_in,
                              void* d_out, int out_size, void* d_ws, size_t ws_size,
                              hipStream_t stream) {
  const float* x = (const float*)d_in[0];
  const float* gamma = (const float*)d_in[1];
  const float* beta = (const float*)d_in[2];
  const float* wq = (const float*)d_in[3];
  const float* wk = (const float*)d_in[5];
  const float* bk = (const float*)d_in[6];
  const float* wv = (const float*)d_in[7];
  const float* bv = (const float*)d_in[8];
  const float* wo = (const float*)d_in[9];
  const float* bo = (const float*)d_in[10];
  float* out = (float*)d_out;
  __bf16* wsb = (__bf16*)d_ws;

  prep<<<72, TPB, 0, stream>>>(wq, wk, bk, wv, wo, wsb);
  mha_fused<<<BATCH, TPB, 0, stream>>>(x, gamma, beta, bv, bo, wsb, out);
}